// Round 8
// baseline (203.446 us; speedup 1.0000x reference)
//
#include <hip/hip_runtime.h>
#include <stdint.h>

typedef unsigned short u16;
typedef __attribute__((ext_vector_type(8))) short   short8;   // 8 x bf16 bits (4 VGPR)
typedef __attribute__((ext_vector_type(8))) u16     ushort8;
typedef __attribute__((ext_vector_type(4))) float   f32x4;
typedef __attribute__((ext_vector_type(16))) float  f32x16;
typedef __attribute__((ext_vector_type(4))) unsigned int u32x4;

#define SEQ   2048
#define NH    16
#define HD    64
#define DM    1024
#define ROWS  8192   // B*S
#define BHN   64     // B*H

// round-to-nearest-even f32 -> bf16
__device__ __forceinline__ u16 f2bf(float f){
  union { float f; uint32_t u; } v; v.f = f;
  return (u16)((v.u + 0x7fffu + ((v.u >> 16) & 1u)) >> 16);
}

__device__ __forceinline__ unsigned cvtpk(float a, float b){
  unsigned r;
  asm("v_cvt_pk_bf16_f32 %0, %1, %2" : "=v"(r) : "v"(a), "v"(b));
  return r;
}

// v_permlane32_swap_b32: a.hi32lanes <-> b.lo32lanes
__device__ __forceinline__ void pswap(unsigned &a, unsigned &b){
  asm volatile("v_permlane32_swap_b32 %0, %1" : "+v"(a), "+v"(b));
}

// exp2 via builtin (v_exp_f32 is a TRANS op: raw inline asm hides the
// trans->valu hazard from the compiler and corrupts results [R5 lesson]).
__device__ __forceinline__ float fexp2(float x){
  return __builtin_amdgcn_exp2f(x);
}

// pairwise sum tree (fp add not reassociable by compiler)
__device__ __forceinline__ float tsum16(const f32x16& s){
  float a0=s[0]+s[1], a1=s[2]+s[3], a2=s[4]+s[5], a3=s[6]+s[7];
  float a4=s[8]+s[9], a5=s[10]+s[11], a6=s[12]+s[13], a7=s[14]+s[15];
  float b0=a0+a1, b1=a2+a3, b2=a4+a5, b3=a6+a7;
  return (b0+b1)+(b2+b3);
}

#define GAS(p) ((const __attribute__((address_space(1))) void*)(p))
#define LAS(p) ((__attribute__((address_space(3))) void*)(p))

// barriers with the waitcnt fused inside one memory-clobbered asm: no memory op
// can be compiler-moved across the completion guarantee [R7 race lesson]
#define BAR()   asm volatile("s_barrier" ::: "memory")
#define BARV6() asm volatile("s_waitcnt vmcnt(6)\n\ts_barrier" ::: "memory")
#define BARV0() asm volatile("s_waitcnt vmcnt(0)\n\ts_barrier" ::: "memory")

// ---------------------------------------------------------------- convert x
__global__ void conv_bf16_kernel(const float* __restrict__ in, u16* __restrict__ out, int n8){
  int i = blockIdx.x * blockDim.x + threadIdx.x;
  if (i >= n8) return;
  const float4* p = (const float4*)in + (size_t)i * 2;
  float4 a = p[0], b = p[1];
  ushort8 o;
  o[0]=f2bf(a.x); o[1]=f2bf(a.y); o[2]=f2bf(a.z); o[3]=f2bf(a.w);
  o[4]=f2bf(b.x); o[5]=f2bf(b.y); o[6]=f2bf(b.z); o[7]=f2bf(b.w);
  *(ushort8*)(out + (size_t)i * 8) = o;
}

// ------------------------------------------- transpose+convert  [R][C] f32 -> [C][R] bf16
__global__ void transpose_conv_kernel(const float* __restrict__ in, u16* __restrict__ out,
                                      int R, int C){
  __shared__ float tile[32][33];
  int c0 = blockIdx.x * 32, r0 = blockIdx.y * 32;
  int tx = threadIdx.x & 31, ty = threadIdx.x >> 5;  // 256 thr: 32x8
  #pragma unroll
  for (int i = 0; i < 4; i++)
    tile[ty + 8*i][tx] = in[(size_t)(r0 + ty + 8*i) * C + c0 + tx];
  __syncthreads();
  #pragma unroll
  for (int i = 0; i < 4; i++)
    out[(size_t)(c0 + ty + 8*i) * R + r0 + tx] = f2bf(tile[tx][ty + 8*i]);
}

// ---------------------------------------------------------------- GEMM 8-phase 256^2 (QKV)
// M=8192 N=3072 K=1024. 8 waves (2Mx4N), BK=64, 128KB LDS (2 buf x {A0,A1,B0,B1} 16KB).
// Race-free stage plan (ledger, R8): ph1 buf1.A0(t1) | ph3 buf0.B0+B1(t2) | ph4 buf0.A1(t2)
// | ph5 buf0.A0(t2) | ph7 buf1.B0+B1(t3) | ph8 buf1.A1(t3). vmcnt(6) ONLY at ph4/ph8:
//   ph4-end newest6 = ph4(2)+ph3(4) -> ph1 stage complete before ph5 reads it;
//   ph8-end newest6 = ph8(2)+ph7(4) -> ph3/4/5 stages complete before next ph1.
__global__ __launch_bounds__(512, 2) void gemm8_kernel(
    const u16* __restrict__ A, const u16* __restrict__ Bt, const float* __restrict__ bias,
    u16* __restrict__ Qo, u16* __restrict__ Ko, u16* __restrict__ Vto)
{
  __shared__ __align__(16) char lds[131072];
  const int tid = threadIdx.x, lane = tid & 63, wv = tid >> 6;
  const int wm = wv >> 2, wn = wv & 3;           // 2x4 wave grid; 128x64 out per wave
  const int l15 = lane & 15, l4 = lane >> 4;

  int bid = blockIdx.x;                          // 384 blocks = 8 XCD x 48
  int nid = (bid & 7) * 48 + (bid >> 3);
  int tm = nid / 12, tn = nid - tm * 12;
  const int m0 = tm * 256, n0 = tn * 256;

  f32x4 acc[8][4] = {};

  // stage one 16KB half-tile (128 rows x 128B), pre-swizzled source, linear LDS dest
  #define STG(REGION, SRC, ROW0, KT) do { \
    _Pragma("unroll") \
    for (int _u = 0; _u < 2; _u++) { \
      int _r = _u*64 + (tid >> 3); \
      int _sb = ((((tid & 7) << 4) ^ ((_r & 7) << 4)) >> 1); \
      const u16* _g = (SRC) + (((size_t)((ROW0) + _r)) << 10) + ((KT) << 6) + _sb; \
      __builtin_amdgcn_global_load_lds(GAS(_g), LAS(lds + (REGION) + _u*8192 + (wv << 10)), 16, 0, 0); \
    } \
  } while (0)

  // prologue: buf0 full (t0) + buf1 {B1,B0,A1} (t1); vmcnt(6) -> buf0's 4 (oldest) done
  STG(0,              A,  m0,       0);
  STG(16384,          A,  m0 + 128, 0);
  STG(32768,          Bt, n0,       0);
  STG(49152,          Bt, n0 + 128, 0);
  STG(65536 + 49152,  Bt, n0 + 128, 1);
  STG(65536 + 32768,  Bt, n0,       1);
  STG(65536 + 16384,  A,  m0 + 128, 1);
  BARV6();

  short8 Af[4][2], Bf[2][2][2];

  #define LD_A(BUF, M) do { \
    _Pragma("unroll") for (int mr = 0; mr < 4; mr++) \
      _Pragma("unroll") for (int kk = 0; kk < 2; kk++) { \
        int row = (M)*64 + mr*16 + l15; \
        Af[mr][kk] = *(const short8*)(lds + (BUF)*65536 + wm*16384 + row*128 \
                       + ((kk*64 + 16*l4) ^ ((row & 7) << 4))); \
      } \
  } while (0)

  #define LD_B(BUF, N) do { \
    _Pragma("unroll") for (int jr = 0; jr < 2; jr++) \
      _Pragma("unroll") for (int kk = 0; kk < 2; kk++) { \
        int row = (wn & 1)*64 + (N)*32 + jr*16 + l15; \
        Bf[N][jr][kk] = *(const short8*)(lds + (BUF)*65536 + 32768 + (wn >> 1)*16384 + row*128 \
                          + ((kk*64 + 16*l4) ^ ((row & 7) << 4))); \
      } \
  } while (0)

  #define MM(M, N) do { \
    __builtin_amdgcn_s_setprio(1); \
    _Pragma("unroll") for (int mr = 0; mr < 4; mr++) \
      _Pragma("unroll") for (int jr = 0; jr < 2; jr++) \
        _Pragma("unroll") for (int kk = 0; kk < 2; kk++) \
          acc[(M)*4 + mr][(N)*2 + jr] = __builtin_amdgcn_mfma_f32_16x16x32_bf16( \
              Af[mr][kk], Bf[N][jr][kk], acc[(M)*4 + mr][(N)*2 + jr], 0, 0, 0); \
    __builtin_amdgcn_s_setprio(0); \
  } while (0)

  for (int i = 0; i < 7; i++) {                 // steady: tiles 2i (buf0), 2i+1 (buf1)
    int t1 = 2*i + 1, t2 = 2*i + 2, t3 = 2*i + 3;   // t3 <= 15, no guards
    // ph1: reads buf0 {A rows0-63, B rows 0-31/64-95}; stage buf1.A0(t1)
    LD_A(0, 0); LD_B(0, 0);
    STG(65536 + 0, A, m0, t1);
    BAR();  MM(0, 0);  BAR();
    // ph2: reads buf0 {B rows 32-63/96-127}
    LD_B(0, 1);
    BAR();  MM(0, 1);  BAR();
    // ph3: reads buf0 {A rows 64-127}; stage buf0.B0+B1(t2) [B free after ph2]
    LD_A(0, 1);
    STG(32768, Bt, n0, t2);
    STG(49152, Bt, n0 + 128, t2);
    BAR();  MM(1, 1);  BAR();
    // ph4: stage buf0.A1(t2) [A free after ph3]; vmcnt(6) -> ph1's buf1.A0 complete
    STG(16384, A, m0 + 128, t2);
    BAR();  MM(1, 0);  BARV6();
    // ph5: reads buf1; stage buf0.A0(t2)
    LD_A(1, 0); LD_B(1, 0);
    STG(0, A, m0, t2);
    BAR();  MM(0, 0);  BAR();
    // ph6
    LD_B(1, 1);
    BAR();  MM(0, 1);  BAR();
    // ph7: stage buf1.B0+B1(t3) [free after ph6]
    LD_A(1, 1);
    STG(65536 + 32768, Bt, n0, t3);
    STG(65536 + 49152, Bt, n0 + 128, t3);
    BAR();  MM(1, 1);  BAR();
    // ph8: stage buf1.A1(t3) [free after ph7]; vmcnt(6) -> ph3/4/5 stages complete
    STG(65536 + 16384, A, m0 + 128, t3);
    BAR();  MM(1, 0);  BARV6();
  }

  // epilogue iteration: tiles 14 (buf0), 15 (buf1); only stage = ph1 buf1.A0(t15)
  LD_A(0, 0); LD_B(0, 0);
  STG(65536 + 0, A, m0, 15);
  BAR();  MM(0, 0);  BAR();
  LD_B(0, 1);
  BAR();  MM(0, 1);  BAR();
  LD_A(0, 1);
  BAR();  MM(1, 1);  BAR();
  BAR();  MM(1, 0);  BARV0();                   // drain: t15.A0 landed before ph5 reads
  LD_A(1, 0); LD_B(1, 0);
  BAR();  MM(0, 0);  BAR();
  LD_B(1, 1);
  BAR();  MM(0, 1);  BAR();
  LD_A(1, 1);
  BAR();  MM(1, 1);  BAR();
  MM(1, 0);

  #undef STG
  #undef LD_A
  #undef LD_B
  #undef MM

  // epilogue: QKV scatter (C/D layout col=lane&15, row=(lane>>4)*4+r)
  const int part = n0 >> 10;                    // 256-tile never crosses q/k/v boundary
  #pragma unroll
  for (int i = 0; i < 8; i++) {
    int row = m0 + wm*128 + i*16 + (l4 << 2);
    int b = row >> 11, s = row & 2047;
    #pragma unroll
    for (int j = 0; j < 4; j++) {
      int col = n0 + wn*64 + j*16 + l15;
      int cn = col & 1023, h = cn >> 6, d = cn & 63;
      int bh = b * NH + h;
      #pragma unroll
      for (int r = 0; r < 4; r++) {
        float v = acc[i][j][r] + bias[col];
        int ss = s + r;
        // Q pre-scale folds 1/sqrt(64) * log2(e) so attention works in exp2 domain
        if (part == 0)      Qo [((size_t)bh*SEQ + ss)*HD + d] = f2bf(v * 0.18033688011f);
        else if (part == 1) Ko [((size_t)bh*SEQ + ss)*HD + d] = f2bf(v);
        else                Vto[((size_t)bh*HD  + d)*SEQ + ss] = f2bf(v);
      }
    }
  }
}

// ---------------------------------------------------------------- GEMM (round-1, verified) - out proj
#define BM 128
#define BN 128
#define BK 64

__global__ __launch_bounds__(256, 2) void gemm_kernel(
    const u16* __restrict__ A, const u16* __restrict__ Bt, const float* __restrict__ bias,
    float* __restrict__ Cout)
{
  __shared__ __align__(16) u16 As[BM * BK];
  __shared__ __align__(16) u16 Bs[BN * BK];
  const int tid  = threadIdx.x;
  const int lane = tid & 63, wv = tid >> 6;
  const int wr = wv >> 1, wc = wv & 1;
  const int m0 = blockIdx.y * BM, n0 = blockIdx.x * BN;
  const int K = 1024;

  f32x4 acc[4][4] = {};

  for (int k0 = 0; k0 < K; k0 += BK) {
    #pragma unroll
    for (int i = 0; i < 4; i++) {
      int f = (i * 256 + tid) * 16;
      int row = f >> 7, inrow = f & 127;
      int src = inrow ^ ((row & 7) << 4);
      const u16* ga = A  + (size_t)(m0 + row) * K + k0 + (src >> 1);
      __builtin_amdgcn_global_load_lds(GAS(ga), LAS((char*)As + (i*256 + (wv<<6))*16), 16, 0, 0);
      const u16* gb = Bt + (size_t)(n0 + row) * K + k0 + (src >> 1);
      __builtin_amdgcn_global_load_lds(GAS(gb), LAS((char*)Bs + (i*256 + (wv<<6))*16), 16, 0, 0);
    }
    __syncthreads();
    #pragma unroll
    for (int kk = 0; kk < 2; kk++) {
      short8 af[4], bfr[4];
      #pragma unroll
      for (int i = 0; i < 4; i++) {
        int row = wr*64 + i*16 + (lane & 15);
        int kb  = (kk*64 + 16*(lane >> 4)) ^ ((row & 7) << 4);
        af[i] = *(const short8*)((const char*)As + row*128 + kb);
      }
      #pragma unroll
      for (int j = 0; j < 4; j++) {
        int row = wc*64 + j*16 + (lane & 15);
        int kb  = (kk*64 + 16*(lane >> 4)) ^ ((row & 7) << 4);
        bfr[j] = *(const short8*)((const char*)Bs + row*128 + kb);
      }
      #pragma unroll
      for (int i = 0; i < 4; i++)
        #pragma unroll
        for (int j = 0; j < 4; j++)
          acc[i][j] = __builtin_amdgcn_mfma_f32_16x16x32_bf16(af[i], bfr[j], acc[i][j], 0, 0, 0);
    }
    __syncthreads();
  }

  #pragma unroll
  for (int i = 0; i < 4; i++) {
    int row = m0 + wr*64 + i*16 + ((lane >> 4) << 2);
    #pragma unroll
    for (int j = 0; j < 4; j++) {
      int col = n0 + wc*64 + j*16 + (lane & 15);
      float bv = bias[col];
      #pragma unroll
      for (int r = 0; r < 4; r++)
        Cout[(size_t)(row + r) * DM + col] = acc[i][j][r] + bv;
    }
  }
}

// ---------------------------------------------------------------- flash attention (R6, verified)
// Fixed-M softmax (M=16 in exp2 domain), 64 q-rows per wave, in-register P via
// cvt_pk+permlane32_swap, dbuf K/V. 4 waves x 64 q = 256 q/block, 512 blocks = 2/CU.
#define STAGE(LOFF, T) do { \
    _Pragma("unroll") \
    for (int _i = 0; _i < 2; _i++) { \
      int _row = _i * 32 + (tid >> 3); \
      int _src = (((tid & 7) << 4) ^ ((_row & 7) << 4)) >> 1; \
      const u16* _gk = Kg + (((size_t)bh * SEQ + (T) * 64 + _row) << 6) + _src; \
      __builtin_amdgcn_global_load_lds(GAS(_gk), LAS(lds + (LOFF) + _i * 4096 + (wv << 10)), 16, 0, 0); \
      const u16* _gv = Vt + ((size_t)(bh * 64 + _row)) * SEQ + (T) * 64 + _src; \
      __builtin_amdgcn_global_load_lds(GAS(_gv), LAS(lds + (LOFF) + 8192 + _i * 4096 + (wv << 10)), 16, 0, 0); \
    } \
  } while (0)

#define WAITBAR() do { \
    asm volatile("s_waitcnt vmcnt(0) lgkmcnt(0)\n\ts_barrier" ::: "memory"); \
  } while (0)

#define PACK_PA(S, PA0, PA1) do { \
    unsigned a0 = cvtpk((S)[0],  (S)[1]),  b0 = cvtpk((S)[4],  (S)[5]); \
    unsigned a1 = cvtpk((S)[2],  (S)[3]),  b1 = cvtpk((S)[6],  (S)[7]); \
    unsigned a2 = cvtpk((S)[8],  (S)[9]),  b2 = cvtpk((S)[12], (S)[13]); \
    unsigned a3 = cvtpk((S)[10], (S)[11]), b3 = cvtpk((S)[14], (S)[15]); \
    pswap(a0, b0); pswap(a1, b1); pswap(a2, b2); pswap(a3, b3); \
    (PA0).u = (u32x4){a0, a1, b0, b1}; \
    (PA1).u = (u32x4){a2, a3, b2, b3}; \
  } while (0)

#define TILE64(BOFF) do { \
    _Pragma("unroll") \
    for (int H = 0; H < 2; H++) { \
      short8 kf[4]; \
      _Pragma("unroll") \
      for (int kd = 0; kd < 4; kd++) \
        kf[kd] = *(const short8*)(lds + (BOFF) + (32*H + l31) * 128 + ((32*kd + 16*hi) ^ swz)); \
      f32x16 sA, sB; \
      _Pragma("unroll") for (int i = 0; i < 16; i++) { sA[i] = -16.f; sB[i] = -16.f; } \
      __builtin_amdgcn_s_setprio(1); \
      _Pragma("unroll") \
      for (int kd = 0; kd < 4; kd++) { \
        sA = __builtin_amdgcn_mfma_f32_32x32x16_bf16(kf[kd], qfA[kd], sA, 0, 0, 0); \
        sB = __builtin_amdgcn_mfma_f32_32x32x16_bf16(kf[kd], qfB[kd], sB, 0, 0, 0); \
      } \
      __builtin_amdgcn_s_setprio(0); \
      _Pragma("unroll") for (int i = 0; i < 16; i++) { sA[i] = fexp2(sA[i]); sB[i] = fexp2(sB[i]); } \
      lpA += tsum16(sA); lpB += tsum16(sB); \
      union { u32x4 u; short8 s8; } paA0, paA1, paB0, paB1; \
      PACK_PA(sA, paA0, paA1); \
      PACK_PA(sB, paB0, paB1); \
      __builtin_amdgcn_s_setprio(1); \
      _Pragma("unroll") \
      for (int ki = 0; ki < 2; ki++) { \
        int vo = (64*H + 32*ki + 16*hi) ^ swz; \
        short8 vb0 = *(const short8*)(lds + (BOFF) + 8192  + l31 * 128 + vo); \
        short8 vb1 = *(const short8*)(lds + (BOFF) + 12288 + l31 * 128 + vo); \
        const short8 pA = ki ? paA1.s8 : paA0.s8; \
        const short8 pB = ki ? paB1.s8 : paB0.s8; \
        oA0 = __builtin_amdgcn_mfma_f32_32x32x16_bf16(pA, vb0, oA0, 0, 0, 0); \
        oA1 = __builtin_amdgcn_mfma_f32_32x32x16_bf16(pA, vb1, oA1, 0, 0, 0); \
        oB0 = __builtin_amdgcn_mfma_f32_32x32x16_bf16(pB, vb0, oB0, 0, 0, 0); \
        oB1 = __builtin_amdgcn_mfma_f32_32x32x16_bf16(pB, vb1, oB1, 0, 0, 0); \
      } \
      __builtin_amdgcn_s_setprio(0); \
    } \
  } while (0)

__global__ __launch_bounds__(256, 2) void attn_kernel(
    const u16* __restrict__ Q, const u16* __restrict__ Kg,
    const u16* __restrict__ Vt, u16* __restrict__ O)
{
  __shared__ __align__(16) char lds[32768];
  const int tid = threadIdx.x, lane = tid & 63, wv = tid >> 6;
  const int l31 = lane & 31, hi = lane >> 5;
  const int swz = (lane & 7) << 4;

  int flat = blockIdx.x;
  int nid = (flat & 7) * 64 + (flat >> 3);
  int bh = nid >> 3;
  int q0 = (nid & 7) * 256;

  short8 qfA[4], qfB[4];
  {
    int qrow = q0 + wv * 64 + l31;
    const u16* qp = Q + (((size_t)bh * SEQ + qrow) << 6) + hi * 8;
    #pragma unroll
    for (int kd = 0; kd < 4; kd++) {
      qfA[kd] = *(const short8*)(qp + kd * 16);
      qfB[kd] = *(const short8*)(qp + 2048 + kd * 16);   // +32 rows * 64
    }
  }

  f32x16 oA0 = {}, oA1 = {}, oB0 = {}, oB1 = {};
  float lpA = 0.f, lpB = 0.f;

  STAGE(0, 0);
  WAITBAR();
  for (int t = 0; t < 32; t += 2) {
    STAGE(16384, t + 1);
    TILE64(0);
    WAITBAR();
    if (t + 2 < 32) STAGE(0, t + 2);
    TILE64(16384);
    WAITBAR();
  }

  float lfA = lpA + __shfl_xor(lpA, 32);
  float lfB = lpB + __shfl_xor(lpB, 32);
  int b = bh >> 4, h = bh & 15;
  int qbase = q0 + wv * 64;
  #pragma unroll
  for (int r = 0; r < 16; r++) {
    int qrow = (r & 3) + 8 * (r >> 2) + 4 * hi;
    float invA = 1.0f / __shfl(lfA, qrow);
    float invB = 1.0f / __shfl(lfB, qrow);
    size_t rowA = ((size_t)(b * SEQ + qbase + qrow) << 10) + h * 64 + l31;
    size_t rowB = rowA + (32u << 10);
    O[rowA]      = f2bf(oA0[r] * invA);
    O[rowA + 32] = f2bf(oA1[r] * invA);
    O[rowB]      = f2bf(oB0[r] * invB);
    O[rowB + 32] = f2bf(oB1[r] * invB);
  }
}

// ---------------------------------------------------------------- launch
extern "C" void kernel_launch(void* const* d_in, const int* in_sizes, int n_in,
                              void* d_out, int out_size, void* d_ws, size_t ws_size,
                              hipStream_t stream)
{
  const float* x     = (const float*)d_in[0];
  const float* w_qkv = (const float*)d_in[1];
  const float* b_qkv = (const float*)d_in[2];
  const float* w_out = (const float*)d_in[3];
  const float* b_out = (const float*)d_in[4];
  float* out = (float*)d_out;

  char* w = (char*)d_ws;
  u16* xb    = (u16*)(w);                  // 16,777,216 B
  u16* wqkvT = (u16*)(w + 16777216);       //  6,291,456 B
  u16* woutT = (u16*)(w + 23068672);       //  2,097,152 B
  u16* Qw    = (u16*)(w + 25165824);       // 16,777,216 B
  u16* Kw    = (u16*)(w + 41943040);       // 16,777,216 B
  u16* Vtw   = (u16*)(w + 58720256);       // 16,777,216 B
  u16* Ow    = (u16*)(w + 75497472);       // 16,777,216 B

  conv_bf16_kernel<<<dim3(4096), dim3(256), 0, stream>>>(x, xb, ROWS * DM / 8);
  transpose_conv_kernel<<<dim3(96, 32), dim3(256), 0, stream>>>(w_qkv, wqkvT, 1024, 3072);
  transpose_conv_kernel<<<dim3(32, 32), dim3(256), 0, stream>>>(w_out, woutT, 1024, 1024);

  gemm8_kernel<<<dim3(384), dim3(512), 0, stream>>>(xb, wqkvT, b_qkv, Qw, Kw, Vtw);
  attn_kernel<<<dim3(512), dim3(256), 0, stream>>>(Qw, Kw, Vtw, Ow);
  gemm_kernel<<<dim3(8, 64), dim3(256), 0, stream>>>(Ow, woutT, b_out, out);
}